// Round 6
// baseline (184.356 us; speedup 1.0000x reference)
//
#include <hip/hip_runtime.h>

// Problem constants (fixed by the reference's setup_inputs).
constexpr int N = 8192;           // row length
constexpr int K = 64;             // top-k
constexpr int THREADS = 256;      // 4 waves/block; ONE ROW PER WAVE, no barriers
constexpr int WPB = THREADS / 64; // 4 rows per block -> grid 512
constexpr int CHUNKS = N / 256;   // 32 chunks: 64 lanes x float4 per chunk
constexpr int WCAP = 256;         // per-wave candidate capacity

// Pre-filter threshold. For N(0,1)+Gumbel rows of 8192:
// E[count(x >= t)] = 8192 * e^(0.5 - t); at t=4.75 -> 117 +- 10.8.
// Rows outside [K, WCAP] take the exact per-wave radix fallback below,
// so this is a speed hint, not a correctness assumption.
constexpr float FTHRESH = 4.75f;

typedef float f32x4 __attribute__((ext_vector_type(4)));

// Map fp32 bits to an unsigned key with the same total order as float
// (fallback path only).
__device__ __forceinline__ unsigned orderable(float f) {
    unsigned x = __float_as_uint(f);
    return (x & 0x80000000u) ? ~x : (x | 0x80000000u);
}

__global__ __launch_bounds__(THREADS, 2)   // 2 blocks/CU, 256-VGPR budget
void gumbel_topk_onehot(const float* __restrict__ logits,
                        const float* __restrict__ noise,
                        float* __restrict__ out)
{
    __shared__ float    cval[WPB][WCAP];   // 4 KB: candidate values (wave-private)
    __shared__ unsigned cidx[WPB][WCAP];   // 4 KB: candidate indices

    const int lane = threadIdx.x & 63;
    const int w    = threadIdx.x >> 6;
    const long long row = (long long)blockIdx.x * WPB + w;

    const f32x4* l4 = (const f32x4*)(logits + row * (long long)N);
    const f32x4* n4 = (const f32x4*)(noise  + row * (long long)N);
    f32x4*       o4 = (f32x4*)(out + row * (long long)N);
    float*     orow = out + row * (long long)N;

    float*    mv = cval[w];
    unsigned* mi = cidx[w];
    const unsigned long long below = (1ull << lane) - 1ull;

    // ======== Pass A: stream row; fuse zero-write; ballot-compact ========
    // No atomics: ballot prefix gives positions; c stays wave-uniform in regs.
    unsigned c = 0;
    f32x4 zero4 = {0.f, 0.f, 0.f, 0.f};
#pragma unroll 8
    for (int ch = 0; ch < CHUNKS; ++ch) {
        f32x4 a = l4[ch * 64 + lane];
        f32x4 b = n4[ch * 64 + lane];
        f32x4 s = a + b;
        __builtin_nontemporal_store(zero4, &o4[ch * 64 + lane]);
        const unsigned ebase = (unsigned)(ch * 256 + lane * 4);
#pragma unroll
        for (int e = 0; e < 4; ++e) {
            const bool p = (s[e] >= FTHRESH);
            unsigned long long m = __ballot(p);
            if (p) {
                unsigned pos = c + (unsigned)__popcll(m & below);
                if (pos < (unsigned)WCAP) { mv[pos] = s[e]; mi[pos] = ebase + e; }
            }
            c += (unsigned)__popcll(m);
        }
    }
    asm volatile("s_waitcnt lgkmcnt(0)" ::: "memory");   // my ds_writes done

    if (c >= (unsigned)K && c <= (unsigned)WCAP) {
        // ======== Common path: in-wave exact rank-count over c candidates ====
        // Every element > T or == T is >= FTHRESH, hence in the candidate list,
        // so both the K-th value and its tie multiplicity are exact.
        const unsigned j1 = lane + 64, j2 = lane + 128, j3 = lane + 192;
        const float v0 = ((unsigned)lane < c) ? mv[lane] : 0.f;
        const float v1 = (j1 < c) ? mv[j1] : 0.f;
        const float v2 = (j2 < c) ? mv[j2] : 0.f;
        const float v3 = (j3 < c) ? mv[j3] : 0.f;
        unsigned g0=0,g1=0,g2=0,g3=0,e0=0,e1=0,e2=0,e3=0;
        for (unsigned j = 0; j < c; ++j) {
            const float vj = mv[j];                      // LDS broadcast
            g0 += vj > v0; e0 += vj == v0;
            g1 += vj > v1; e1 += vj == v1;
            g2 += vj > v2; e2 += vj == v2;
            g3 += vj > v3; e3 += vj == v3;
        }
        // K-th largest = unique VALUE with g < K <= g+eq (dup holders agree).
        const bool f0 = ((unsigned)lane < c) && g0 < (unsigned)K && g0 + e0 >= (unsigned)K;
        const bool f1 = (j1 < c) && g1 < (unsigned)K && g1 + e1 >= (unsigned)K;
        const bool f2 = (j2 < c) && g2 < (unsigned)K && g2 + e2 >= (unsigned)K;
        const bool f3 = (j3 < c) && g3 < (unsigned)K && g3 + e3 >= (unsigned)K;
        float t = 0.f; unsigned tk = 0, ce = 0;
        if (f0) { t = v0; tk = (unsigned)K - g0; ce = e0; }
        if (f1) { t = v1; tk = (unsigned)K - g1; ce = e1; }
        if (f2) { t = v2; tk = (unsigned)K - g2; ce = e2; }
        if (f3) { t = v3; tk = (unsigned)K - g3; ce = e3; }
        const unsigned long long fm = __ballot(f0 | f1 | f2 | f3);
        const int src = __ffsll((long long)fm) - 1;
        const float Tf = __shfl(t, src);
        const unsigned take_eq = (unsigned)__shfl((int)tk, src);
        const unsigned c_eq    = (unsigned)__shfl((int)ce, src);
        const bool fast = (take_eq == c_eq);

        asm volatile("s_waitcnt vmcnt(0)" ::: "memory"); // zero-stores landed
        // Sparse scatter of the ~K ones (same wave wrote the zeros -> ordered).
        if ((unsigned)lane < c && (v0 > Tf || (fast && v0 == Tf))) orow[mi[lane]] = 1.0f;
        if (j1 < c && (v1 > Tf || (fast && v1 == Tf))) orow[mi[j1]] = 1.0f;
        if (j2 < c && (v2 > Tf || (fast && v2 == Tf))) orow[mi[j2]] = 1.0f;
        if (j3 < c && (v3 > Tf || (fast && v3 == Tf))) orow[mi[j3]] = 1.0f;

        if (!fast) {
            // Tie straddles boundary: lowest indices win (jax.lax.top_k).
            const unsigned i0 = ((unsigned)lane < c) ? mi[lane] : 0u;
            const unsigned i1 = (j1 < c) ? mi[j1] : 0u;
            const unsigned i2 = (j2 < c) ? mi[j2] : 0u;
            const unsigned i3 = (j3 < c) ? mi[j3] : 0u;
            unsigned r0=0,r1=0,r2=0,r3=0;
            for (unsigned j = 0; j < c; ++j) {
                const bool q = (mv[j] == Tf);
                const unsigned ij = mi[j];
                r0 += q && (ij < i0); r1 += q && (ij < i1);
                r2 += q && (ij < i2); r3 += q && (ij < i3);
            }
            if ((unsigned)lane < c && v0 == Tf && r0 < take_eq) orow[i0] = 1.0f;
            if (j1 < c && v1 == Tf && r1 < take_eq) orow[i1] = 1.0f;
            if (j2 < c && v2 == Tf && r2 < take_eq) orow[i2] = 1.0f;
            if (j3 < c && v3 == Tf && r3 < take_eq) orow[i3] = 1.0f;
        }
    } else {
        // ======== Rare fallback: per-wave exact 4-round byte radix ========
        unsigned* wh = (unsigned*)mv;            // 256 bins alias cval[w] (1 KB)
        unsigned prefix = 0, kth = (unsigned)K, ceq = 0;
#pragma unroll 1
        for (int rnd = 0; rnd < 4; ++rnd) {
            const int shift = 24 - 8 * rnd;
            wh[lane] = 0; wh[lane+64] = 0; wh[lane+128] = 0; wh[lane+192] = 0;
            asm volatile("s_waitcnt lgkmcnt(0)" ::: "memory");
            for (int ch = 0; ch < CHUNKS; ++ch) {
                f32x4 a = l4[ch * 64 + lane];
                f32x4 b = n4[ch * 64 + lane];
#pragma unroll
                for (int e = 0; e < 4; ++e) {
                    const unsigned key = orderable(a[e] + b[e]);
                    const bool in = (rnd == 0) || ((key >> (unsigned)(shift + 8)) == prefix);
                    if (in) atomicAdd(&wh[(key >> shift) & 255u], 1u);
                }
            }
            asm volatile("s_waitcnt lgkmcnt(0)" ::: "memory");
            const unsigned h0 = wh[4*lane+0], h1 = wh[4*lane+1];
            const unsigned h2 = wh[4*lane+2], h3 = wh[4*lane+3];
            const unsigned p = h0 + h1 + h2 + h3;
            unsigned S = p;
#pragma unroll
            for (int off = 1; off < 64; off <<= 1) {
                const unsigned v = __shfl_down(S, off);
                if (lane + off < 64) S += v;
            }
            const unsigned Snext = S - p;
            const bool win = (S >= kth) && (Snext < kth);
            unsigned bin = 0, nk = 0, bc = 0;
            if (win) {
                unsigned cum = Snext;
                if (cum + h3 >= kth)      { bin = 4u*lane+3; nk = kth - cum; bc = h3; }
                else { cum += h3;
                if (cum + h2 >= kth)      { bin = 4u*lane+2; nk = kth - cum; bc = h2; }
                else { cum += h2;
                if (cum + h1 >= kth)      { bin = 4u*lane+1; nk = kth - cum; bc = h1; }
                else { cum += h1;
                                            bin = 4u*lane+0; nk = kth - cum; bc = h0; } } }
            }
            const unsigned long long wm = __ballot(win);
            const int src = __ffsll((long long)wm) - 1;
            bin = (unsigned)__shfl((int)bin, src);
            kth = (unsigned)__shfl((int)nk, src);
            ceq = (unsigned)__shfl((int)bc, src);
            prefix = (prefix << 8) | bin;
        }
        const unsigned Tord = prefix;            // exact K-th largest key
        const unsigned take_eq = kth;
        const bool fast = (take_eq == ceq);

        asm volatile("s_waitcnt vmcnt(0)" ::: "memory"); // zeros landed
        unsigned rem = take_eq;
        for (int ch = 0; ch < CHUNKS; ++ch) {
            f32x4 a = l4[ch * 64 + lane];
            f32x4 b = n4[ch * 64 + lane];
            const unsigned k0 = orderable(a[0] + b[0]);
            const unsigned k1 = orderable(a[1] + b[1]);
            const unsigned k2 = orderable(a[2] + b[2]);
            const unsigned k3 = orderable(a[3] + b[3]);
            const unsigned ebase = (unsigned)(ch * 256 + lane * 4);
            if (fast) {
                if (k0 >= Tord) orow[ebase+0] = 1.0f;
                if (k1 >= Tord) orow[ebase+1] = 1.0f;
                if (k2 >= Tord) orow[ebase+2] = 1.0f;
                if (k3 >= Tord) orow[ebase+3] = 1.0f;
            } else {
                if (k0 > Tord) orow[ebase+0] = 1.0f;
                if (k1 > Tord) orow[ebase+1] = 1.0f;
                if (k2 > Tord) orow[ebase+2] = 1.0f;
                if (k3 > Tord) orow[ebase+3] = 1.0f;
                // index-ordered tie take (lane-major order == index order)
                const unsigned long long b0 = __ballot(k0 == Tord);
                const unsigned long long b1 = __ballot(k1 == Tord);
                const unsigned long long b2 = __ballot(k2 == Tord);
                const unsigned long long b3 = __ballot(k3 == Tord);
                if (rem) {
                    unsigned r = (unsigned)(__popcll(b0 & below) + __popcll(b1 & below)
                                          + __popcll(b2 & below) + __popcll(b3 & below));
                    if (k0 == Tord) { if (r < rem) orow[ebase+0] = 1.0f; ++r; }
                    if (k1 == Tord) { if (r < rem) orow[ebase+1] = 1.0f; ++r; }
                    if (k2 == Tord) { if (r < rem) orow[ebase+2] = 1.0f; ++r; }
                    if (k3 == Tord) { if (r < rem) orow[ebase+3] = 1.0f; ++r; }
                }
                const unsigned tot = (unsigned)(__popcll(b0) + __popcll(b1)
                                              + __popcll(b2) + __popcll(b3));
                rem = (rem > tot) ? rem - tot : 0u;
            }
        }
    }
}

extern "C" void kernel_launch(void* const* d_in, const int* in_sizes, int n_in,
                              void* d_out, int out_size, void* d_ws, size_t ws_size,
                              hipStream_t stream) {
    const float* logits = (const float*)d_in[0];
    const float* noise  = (const float*)d_in[1];
    float* out = (float*)d_out;
    const int rows = in_sizes[0] / N;   // 2048
    gumbel_topk_onehot<<<rows / WPB, THREADS, 0, stream>>>(logits, noise, out);
}

// Round 7
// 173.714 us; speedup vs baseline: 1.0613x; 1.0613x over previous
//
#include <hip/hip_runtime.h>

// Problem constants (fixed by the reference's setup_inputs).
constexpr int N = 8192;          // row length
constexpr int K = 64;            // top-k
constexpr int THREADS = 512;     // 8 waves/block, grid 2048
constexpr int WAVES = THREADS / 64;
constexpr int EPT = N / THREADS; // 16 elements per thread (in registers)
constexpr int VEC = EPT / 4;     // 4 float4 loads per thread per operand
constexpr int CAP = 1024;        // candidate buffer capacity (4 KB)

// Pre-filter threshold. For N(0,1)+Gumbel rows of 8192:
// E[count(x >= t)] = 8192 * e^(0.5 - t); at t=4.75 -> 117 +- 10.8.
// P(count < 64) ~ 5e-7 per row. Rows outside [K, 512] take the exact
// full-radix fallback, so this is a speed hint, not a correctness assumption.
constexpr float FTHRESH = 4.75f;

typedef float f32x4 __attribute__((ext_vector_type(4)));

// Map fp32 bits to an unsigned key with the same total order as float
// (fallback path only).
__device__ __forceinline__ unsigned orderable(float f) {
    unsigned x = __float_as_uint(f);
    return (x & 0x80000000u) ? ~x : (x | 0x80000000u);
}

// Barrier that does NOT drain vmcnt (LDS-communication barriers only).
__device__ __forceinline__ void barrier_nd() {
    asm volatile("s_waitcnt lgkmcnt(0)" ::: "memory");
    __builtin_amdgcn_s_barrier();
    asm volatile("" ::: "memory");
}

// (512,4): 128-VGPR budget. At (512,8)/64-VGPR the compiler schedules for
// min pressure (VGPR_Count 24-32 across R4-R6) and chops the load stream
// into ~2-4 outstanding loads per wave -> ~2 TB/s plateau. Here we force
// all 8 float4 loads (64 VGPRs of destinations) live simultaneously.
__global__ __launch_bounds__(THREADS, 4)
void gumbel_topk_onehot(const float* __restrict__ logits,
                        const float* __restrict__ noise,
                        float* __restrict__ out)
{
    __shared__ __align__(16) unsigned hist[2048];   // 8 KB (fallback only)
    __shared__ __align__(16) unsigned cand[CAP];    // 4 KB
    __shared__ unsigned wavesum[WAVES];
    __shared__ unsigned ccount;
    __shared__ unsigned sel_bin, sel_kth, sel_cnt;
    __shared__ unsigned r_val, r_take, r_ceq;

    const int tid  = threadIdx.x;
    const int lane = tid & 63;
    const int wave = tid >> 6;
    const long long row = blockIdx.x;

    if (tid == 0) ccount = 0u;

    // ---- Load row: ALL 8 float4 issued and pinned live before any use ----
    const f32x4* l4 = (const f32x4*)(logits + row * (long long)N);
    const f32x4* n4 = (const f32x4*)(noise  + row * (long long)N);
    f32x4 av[VEC], bv[VEC];
#pragma unroll
    for (int i = 0; i < VEC; ++i) av[i] = l4[tid + i * THREADS];
#pragma unroll
    for (int i = 0; i < VEC; ++i) bv[i] = n4[tid + i * THREADS];
    // Pin every load result: forces all 8 global_load_dwordx4 per lane to be
    // in flight together (8 KB/wave outstanding) instead of stall-and-drain
    // batches of 2. Empty asm = zero instructions, register-allocation only.
#pragma unroll
    for (int i = 0; i < VEC; ++i)
        asm volatile("" : "+v"(av[i]), "+v"(bv[i]));

    float s[EPT];
#pragma unroll
    for (int i = 0; i < VEC; ++i) {
        s[4*i+0] = av[i].x + bv[i].x;
        s[4*i+1] = av[i].y + bv[i].y;
        s[4*i+2] = av[i].z + bv[i].z;
        s[4*i+3] = av[i].w + bv[i].w;
    }
    barrier_nd();                       // ccount=0 visible (overlapped load flight)

    // ---- Sparse compaction of qualifiers (s >= FTHRESH), ~117/row ----
    // Plain predicated atomicAdd: LLVM's atomic optimizer lowers this to
    // ballot + mbcnt + one atomic per wave — aggregation for free.
#pragma unroll
    for (int e = 0; e < EPT; ++e) {
        if (s[e] >= FTHRESH) {
            unsigned pos = atomicAdd(&ccount, 1u);
            if (pos < (unsigned)CAP) cand[pos] = __float_as_uint(s[e]);
        }
    }
    barrier_nd();                       // cand[] + ccount complete

    const unsigned c = ccount;
    float Tf;                           // K-th largest value (as float)
    unsigned take_eq, c_eq;

    if (c >= (unsigned)K && c <= (unsigned)THREADS) {
        // ======== Common path: exact rank-count among the c candidates ========
        // All candidates are positive floats -> uint bit compare == float
        // compare. Elements below FTHRESH are smaller than every candidate.
        const bool have = (tid < (int)c);
        const unsigned myv = have ? cand[tid] : 0u;
        if (tid < (int)((c + 63u) & ~63u)) {            // idle waves -> barrier
            unsigned g = 0, eq = 0;
            int j = 0;
            for (; j + 4 <= (int)c; j += 4) {
                uint4 v = ((const uint4*)cand)[j >> 2]; // 16B broadcast read
                g  += (v.x >  myv) + (v.y >  myv) + (v.z >  myv) + (v.w >  myv);
                eq += (v.x == myv) + (v.y == myv) + (v.z == myv) + (v.w == myv);
            }
            for (; j < (int)c; ++j) {
                unsigned v = cand[j];
                g += (v > myv); eq += (v == myv);
            }
            // K-th largest = unique value with g < K <= g+eq. All threads
            // holding it write identical results (benign race).
            if (have && g < (unsigned)K && g + eq >= (unsigned)K) {
                r_val  = myv;
                r_take = (unsigned)K - g;
                r_ceq  = eq;
            }
        }
        barrier_nd();
        Tf      = __uint_as_float(r_val);
        take_eq = r_take;
        c_eq    = r_ceq;
    } else {
        // ======== Rare fallback: exact 3-round radix select (any input) ========
        unsigned kth = K;

#define SELECT_BIN(BPT)                                                      \
        {                                                                    \
            unsigned p = 0;                                                  \
            _Pragma("unroll")                                                \
            for (int j = 0; j < (BPT); ++j) p += hist[tid * (BPT) + j];      \
            unsigned sc = p;                                                 \
            _Pragma("unroll")                                                \
            for (int off = 1; off < 64; off <<= 1) {                         \
                unsigned v = __shfl_down(sc, off);                           \
                if (lane + off < 64) sc += v;                                \
            }                                                                \
            if (lane == 0) wavesum[wave] = sc;                               \
            __syncthreads();                                                 \
            unsigned S = sc;                                                 \
            _Pragma("unroll")                                                \
            for (int w = 0; w < WAVES; ++w) if (w > wave) S += wavesum[w];   \
            unsigned Snext = S - p;                                          \
            if (S >= kth && Snext < kth) {                                   \
                unsigned cum = Snext;                                        \
                for (int j = (BPT) - 1; j >= 0; --j) {                       \
                    unsigned b = tid * (BPT) + j;                            \
                    unsigned cc = hist[b];                                   \
                    if (cum + cc >= kth) {                                   \
                        sel_bin = b;                                         \
                        sel_kth = kth - cum;                                 \
                        sel_cnt = cc;                                        \
                        break;                                               \
                    }                                                        \
                    cum += cc;                                               \
                }                                                            \
            }                                                                \
            __syncthreads();                                                 \
        }

        // Round 1: bits [31:21] of orderable keys
        ((uint4*)hist)[tid] = make_uint4(0u, 0u, 0u, 0u);
        if (tid == 0) ccount = 0u;
        __syncthreads();
#pragma unroll
        for (int e = 0; e < EPT; ++e)
            atomicAdd(&hist[orderable(s[e]) >> 21], 1u);
        __syncthreads();
        SELECT_BIN(4)
        const unsigned b1   = sel_bin;
        const unsigned cnt1 = sel_cnt;
        kth = sel_kth;

        // Compact round-1 survivors (low 21 bits)
#pragma unroll
        for (int e = 0; e < EPT; ++e) {
            unsigned k_e = orderable(s[e]);
            if ((k_e >> 21) == b1) {
                unsigned pos = atomicAdd(&ccount, 1u);
                if (pos < (unsigned)CAP) cand[pos] = k_e & 0x1FFFFFu;
            }
        }
        __syncthreads();
        const bool use_cand = (cnt1 <= (unsigned)CAP);

        // Round 2: bits [20:10]
        ((uint4*)hist)[tid] = make_uint4(0u, 0u, 0u, 0u);
        __syncthreads();
        if (use_cand) {
            for (int i = tid; i < (int)cnt1; i += THREADS)
                atomicAdd(&hist[cand[i] >> 10], 1u);
        } else {
#pragma unroll
            for (int e = 0; e < EPT; ++e) {
                unsigned k_e = orderable(s[e]);
                if ((k_e >> 21) == b1)
                    atomicAdd(&hist[(k_e >> 10) & 0x7FFu], 1u);
            }
        }
        __syncthreads();
        SELECT_BIN(4)
        const unsigned b2 = sel_bin;
        kth = sel_kth;
        __syncthreads();

        // Round 3: bits [9:0]
        if (tid < 256) ((uint4*)hist)[tid] = make_uint4(0u, 0u, 0u, 0u);
        __syncthreads();
        if (use_cand) {
            for (int i = tid; i < (int)cnt1; i += THREADS) {
                unsigned cv = cand[i];
                if ((cv >> 10) == b2) atomicAdd(&hist[cv & 0x3FFu], 1u);
            }
        } else {
            const unsigned pfx = (b1 << 11) | b2;
#pragma unroll
            for (int e = 0; e < EPT; ++e) {
                unsigned k_e = orderable(s[e]);
                if ((k_e >> 10) == pfx)
                    atomicAdd(&hist[k_e & 0x3FFu], 1u);
            }
        }
        __syncthreads();
        SELECT_BIN(2)
        const unsigned T_ord = (b1 << 21) | (b2 << 10) | sel_bin;
        // Invert orderable(): high bit set -> nonnegative float, else negative.
        const unsigned bits = (T_ord & 0x80000000u) ? (T_ord & 0x7FFFFFFFu)
                                                    : ~T_ord;
        Tf      = __uint_as_float(bits);
        take_eq = sel_kth;
        c_eq    = sel_cnt;
#undef SELECT_BIN
    }

    const bool fast = (take_eq == c_eq);    // no boundary-straddling tie

    // ---- Write one-hot output from registers (non-temporal) ----
    // fast: top-K = { s >= Tf }.  !fast: { s > Tf } now, ties fixed below.
    f32x4* orow = (f32x4*)(out + row * (long long)N);
    if (fast) {
#pragma unroll
        for (int i = 0; i < VEC; ++i) {
            f32x4 o;
            o.x = (s[4*i+0] >= Tf) ? 1.0f : 0.0f;
            o.y = (s[4*i+1] >= Tf) ? 1.0f : 0.0f;
            o.z = (s[4*i+2] >= Tf) ? 1.0f : 0.0f;
            o.w = (s[4*i+3] >= Tf) ? 1.0f : 0.0f;
            __builtin_nontemporal_store(o, &orow[tid + i * THREADS]);
        }
    } else {
#pragma unroll
        for (int i = 0; i < VEC; ++i) {
            f32x4 o;
            o.x = (s[4*i+0] > Tf) ? 1.0f : 0.0f;
            o.y = (s[4*i+1] > Tf) ? 1.0f : 0.0f;
            o.z = (s[4*i+2] > Tf) ? 1.0f : 0.0f;
            o.w = (s[4*i+3] > Tf) ? 1.0f : 0.0f;
            __builtin_nontemporal_store(o, &orow[tid + i * THREADS]);
        }
        // Tie group straddles the boundary — lowest indices win
        // (jax.lax.top_k semantics). Recompute serially from global.
        __syncthreads();   // full drain: one-hot stores done before rewrite
        if (tid == 0) {
            const float* lf = logits + row * (long long)N;
            const float* nf = noise  + row * (long long)N;
            float* of = out + row * (long long)N;
            unsigned cc = 0;
            for (int i = 0; i < N; ++i) {
                if (lf[i] + nf[i] == Tf) {
                    of[i] = 1.0f;
                    if (++cc == take_eq) break;
                }
            }
        }
    }
}

extern "C" void kernel_launch(void* const* d_in, const int* in_sizes, int n_in,
                              void* d_out, int out_size, void* d_ws, size_t ws_size,
                              hipStream_t stream) {
    const float* logits = (const float*)d_in[0];
    const float* noise  = (const float*)d_in[1];
    float* out = (float*)d_out;
    const int rows = in_sizes[0] / N;   // 2048
    gumbel_topk_onehot<<<rows, THREADS, 0, stream>>>(logits, noise, out);
}

// Round 8
// 172.492 us; speedup vs baseline: 1.0688x; 1.0071x over previous
//
#include <hip/hip_runtime.h>

// Problem constants (fixed by the reference's setup_inputs).
constexpr int N = 8192;          // row length
constexpr int K = 64;            // top-k
constexpr int THREADS = 512;     // 8 waves/block, grid 2048
constexpr int WAVES = THREADS / 64;
constexpr int EPT = N / THREADS; // 16 elements per thread (in registers)
constexpr int VEC = EPT / 4;     // 4 float4 loads per thread per operand
constexpr int CAP = 1024;        // candidate buffer capacity (4 KB)

// Pre-filter threshold. For N(0,1)+Gumbel rows of 8192:
// E[count(x >= t)] = 8192 * e^(0.5 - t); at t=4.75 -> 117 +- 10.8.
// P(count < 64) ~ 5e-7 per row. Rows outside [K, 512] take the exact
// full-radix fallback, so this is a speed hint, not a correctness assumption.
constexpr float FTHRESH = 4.75f;

typedef float f32x4 __attribute__((ext_vector_type(4)));

// Map fp32 bits to an unsigned key with the same total order as float
// (fallback path only).
__device__ __forceinline__ unsigned orderable(float f) {
    unsigned x = __float_as_uint(f);
    return (x & 0x80000000u) ? ~x : (x | 0x80000000u);
}

// Barrier that does NOT drain vmcnt (LDS-communication barriers only).
__device__ __forceinline__ void barrier_nd() {
    asm volatile("s_waitcnt lgkmcnt(0)" ::: "memory");
    __builtin_amdgcn_s_barrier();
    asm volatile("" ::: "memory");
}

__global__ __launch_bounds__(THREADS, 4)
void gumbel_topk_onehot(const float* __restrict__ logits,
                        const float* __restrict__ noise,
                        float* __restrict__ out)
{
    __shared__ __align__(16) unsigned hist[2048];   // 8 KB (fallback only)
    __shared__ __align__(16) unsigned cand[CAP];    // 4 KB
    __shared__ unsigned wavesum[WAVES];
    __shared__ unsigned ccount;
    __shared__ unsigned sel_bin, sel_kth, sel_cnt;
    __shared__ unsigned r_val, r_take, r_ceq;

    const int tid  = threadIdx.x;
    const int lane = tid & 63;
    const int wave = tid >> 6;
    const long long row = blockIdx.x;

    if (tid == 0) ccount = 0u;

    // ---- Load row: ALL 8 float4 issued and held live before any use ----
    const f32x4* l4 = (const f32x4*)(logits + row * (long long)N);
    const f32x4* n4 = (const f32x4*)(noise  + row * (long long)N);
    f32x4 av[VEC], bv[VEC];
#pragma unroll
    for (int i = 0; i < VEC; ++i) av[i] = l4[tid + i * THREADS];
#pragma unroll
    for (int i = 0; i < VEC; ++i) bv[i] = n4[tid + i * THREADS];
    // ONE pin with ALL 16 vectors as operands: every global_load_dwordx4 must
    // be issued before this point and all destinations (64 VGPRs) are live
    // simultaneously -> the full 8KB/wave is outstanding in one round trip.
    // (Round 7 used 8 separate pins; the compiler legally pipelined pairs and
    // kept VGPR_Count at 36 -> experiment void.)
    asm volatile(""
        : "+v"(av[0]), "+v"(av[1]), "+v"(av[2]), "+v"(av[3]),
          "+v"(bv[0]), "+v"(bv[1]), "+v"(bv[2]), "+v"(bv[3])
        :
        : "memory");

    float s[EPT];
#pragma unroll
    for (int i = 0; i < VEC; ++i) {
        s[4*i+0] = av[i].x + bv[i].x;
        s[4*i+1] = av[i].y + bv[i].y;
        s[4*i+2] = av[i].z + bv[i].z;
        s[4*i+3] = av[i].w + bv[i].w;
    }
    barrier_nd();                       // ccount=0 visible (overlapped load flight)

    // ---- Sparse compaction of qualifiers (s >= FTHRESH), ~117/row ----
    // Plain predicated atomicAdd: LLVM's atomic optimizer lowers this to
    // ballot + mbcnt + one atomic per wave — aggregation for free.
#pragma unroll
    for (int e = 0; e < EPT; ++e) {
        if (s[e] >= FTHRESH) {
            unsigned pos = atomicAdd(&ccount, 1u);
            if (pos < (unsigned)CAP) cand[pos] = __float_as_uint(s[e]);
        }
    }
    barrier_nd();                       // cand[] + ccount complete

    const unsigned c = ccount;
    float Tf;                           // K-th largest value (as float)
    unsigned take_eq, c_eq;

    if (c >= (unsigned)K && c <= (unsigned)THREADS) {
        // ======== Common path: exact rank-count among the c candidates ========
        // All candidates are positive floats -> uint bit compare == float
        // compare. Elements below FTHRESH are smaller than every candidate.
        const bool have = (tid < (int)c);
        const unsigned myv = have ? cand[tid] : 0u;
        if (tid < (int)((c + 63u) & ~63u)) {            // idle waves -> barrier
            unsigned g = 0, eq = 0;
            int j = 0;
            for (; j + 4 <= (int)c; j += 4) {
                uint4 v = ((const uint4*)cand)[j >> 2]; // 16B broadcast read
                g  += (v.x >  myv) + (v.y >  myv) + (v.z >  myv) + (v.w >  myv);
                eq += (v.x == myv) + (v.y == myv) + (v.z == myv) + (v.w == myv);
            }
            for (; j < (int)c; ++j) {
                unsigned v = cand[j];
                g += (v > myv); eq += (v == myv);
            }
            // K-th largest = unique value with g < K <= g+eq. All threads
            // holding it write identical results (benign race).
            if (have && g < (unsigned)K && g + eq >= (unsigned)K) {
                r_val  = myv;
                r_take = (unsigned)K - g;
                r_ceq  = eq;
            }
        }
        barrier_nd();
        Tf      = __uint_as_float(r_val);
        take_eq = r_take;
        c_eq    = r_ceq;
    } else {
        // ======== Rare fallback: exact 3-round radix select (any input) ========
        unsigned kth = K;

#define SELECT_BIN(BPT)                                                      \
        {                                                                    \
            unsigned p = 0;                                                  \
            _Pragma("unroll")                                                \
            for (int j = 0; j < (BPT); ++j) p += hist[tid * (BPT) + j];      \
            unsigned sc = p;                                                 \
            _Pragma("unroll")                                                \
            for (int off = 1; off < 64; off <<= 1) {                         \
                unsigned v = __shfl_down(sc, off);                           \
                if (lane + off < 64) sc += v;                                \
            }                                                                \
            if (lane == 0) wavesum[wave] = sc;                               \
            __syncthreads();                                                 \
            unsigned S = sc;                                                 \
            _Pragma("unroll")                                                \
            for (int w = 0; w < WAVES; ++w) if (w > wave) S += wavesum[w];   \
            unsigned Snext = S - p;                                          \
            if (S >= kth && Snext < kth) {                                   \
                unsigned cum = Snext;                                        \
                for (int j = (BPT) - 1; j >= 0; --j) {                       \
                    unsigned b = tid * (BPT) + j;                            \
                    unsigned cc = hist[b];                                   \
                    if (cum + cc >= kth) {                                   \
                        sel_bin = b;                                         \
                        sel_kth = kth - cum;                                 \
                        sel_cnt = cc;                                        \
                        break;                                               \
                    }                                                        \
                    cum += cc;                                               \
                }                                                            \
            }                                                                \
            __syncthreads();                                                 \
        }

        // Round 1: bits [31:21] of orderable keys
        ((uint4*)hist)[tid] = make_uint4(0u, 0u, 0u, 0u);
        if (tid == 0) ccount = 0u;
        __syncthreads();
#pragma unroll
        for (int e = 0; e < EPT; ++e)
            atomicAdd(&hist[orderable(s[e]) >> 21], 1u);
        __syncthreads();
        SELECT_BIN(4)
        const unsigned b1   = sel_bin;
        const unsigned cnt1 = sel_cnt;
        kth = sel_kth;

        // Compact round-1 survivors (low 21 bits)
#pragma unroll
        for (int e = 0; e < EPT; ++e) {
            unsigned k_e = orderable(s[e]);
            if ((k_e >> 21) == b1) {
                unsigned pos = atomicAdd(&ccount, 1u);
                if (pos < (unsigned)CAP) cand[pos] = k_e & 0x1FFFFFu;
            }
        }
        __syncthreads();
        const bool use_cand = (cnt1 <= (unsigned)CAP);

        // Round 2: bits [20:10]
        ((uint4*)hist)[tid] = make_uint4(0u, 0u, 0u, 0u);
        __syncthreads();
        if (use_cand) {
            for (int i = tid; i < (int)cnt1; i += THREADS)
                atomicAdd(&hist[cand[i] >> 10], 1u);
        } else {
#pragma unroll
            for (int e = 0; e < EPT; ++e) {
                unsigned k_e = orderable(s[e]);
                if ((k_e >> 21) == b1)
                    atomicAdd(&hist[(k_e >> 10) & 0x7FFu], 1u);
            }
        }
        __syncthreads();
        SELECT_BIN(4)
        const unsigned b2 = sel_bin;
        kth = sel_kth;
        __syncthreads();

        // Round 3: bits [9:0]
        if (tid < 256) ((uint4*)hist)[tid] = make_uint4(0u, 0u, 0u, 0u);
        __syncthreads();
        if (use_cand) {
            for (int i = tid; i < (int)cnt1; i += THREADS) {
                unsigned cv = cand[i];
                if ((cv >> 10) == b2) atomicAdd(&hist[cv & 0x3FFu], 1u);
            }
        } else {
            const unsigned pfx = (b1 << 11) | b2;
#pragma unroll
            for (int e = 0; e < EPT; ++e) {
                unsigned k_e = orderable(s[e]);
                if ((k_e >> 10) == pfx)
                    atomicAdd(&hist[k_e & 0x3FFu], 1u);
            }
        }
        __syncthreads();
        SELECT_BIN(2)
        const unsigned T_ord = (b1 << 21) | (b2 << 10) | sel_bin;
        // Invert orderable(): high bit set -> nonnegative float, else negative.
        const unsigned bits = (T_ord & 0x80000000u) ? (T_ord & 0x7FFFFFFFu)
                                                    : ~T_ord;
        Tf      = __uint_as_float(bits);
        take_eq = sel_kth;
        c_eq    = sel_cnt;
#undef SELECT_BIN
    }

    const bool fast = (take_eq == c_eq);    // no boundary-straddling tie

    // ---- Write one-hot output from registers (non-temporal) ----
    // fast: top-K = { s >= Tf }.  !fast: { s > Tf } now, ties fixed below.
    f32x4* orow = (f32x4*)(out + row * (long long)N);
    if (fast) {
#pragma unroll
        for (int i = 0; i < VEC; ++i) {
            f32x4 o;
            o.x = (s[4*i+0] >= Tf) ? 1.0f : 0.0f;
            o.y = (s[4*i+1] >= Tf) ? 1.0f : 0.0f;
            o.z = (s[4*i+2] >= Tf) ? 1.0f : 0.0f;
            o.w = (s[4*i+3] >= Tf) ? 1.0f : 0.0f;
            __builtin_nontemporal_store(o, &orow[tid + i * THREADS]);
        }
    } else {
#pragma unroll
        for (int i = 0; i < VEC; ++i) {
            f32x4 o;
            o.x = (s[4*i+0] > Tf) ? 1.0f : 0.0f;
            o.y = (s[4*i+1] > Tf) ? 1.0f : 0.0f;
            o.z = (s[4*i+2] > Tf) ? 1.0f : 0.0f;
            o.w = (s[4*i+3] > Tf) ? 1.0f : 0.0f;
            __builtin_nontemporal_store(o, &orow[tid + i * THREADS]);
        }
        // Tie group straddles the boundary — lowest indices win
        // (jax.lax.top_k semantics). Recompute serially from global.
        __syncthreads();   // full drain: one-hot stores done before rewrite
        if (tid == 0) {
            const float* lf = logits + row * (long long)N;
            const float* nf = noise  + row * (long long)N;
            float* of = out + row * (long long)N;
            unsigned cc = 0;
            for (int i = 0; i < N; ++i) {
                if (lf[i] + nf[i] == Tf) {
                    of[i] = 1.0f;
                    if (++cc == take_eq) break;
                }
            }
        }
    }
}

extern "C" void kernel_launch(void* const* d_in, const int* in_sizes, int n_in,
                              void* d_out, int out_size, void* d_ws, size_t ws_size,
                              hipStream_t stream) {
    const float* logits = (const float*)d_in[0];
    const float* noise  = (const float*)d_in[1];
    float* out = (float*)d_out;
    const int rows = in_sizes[0] / N;   // 2048
    gumbel_topk_onehot<<<rows, THREADS, 0, stream>>>(logits, noise, out);
}